// Round 13
// baseline (452.124 us; speedup 1.0000x reference)
//
#include <hip/hip_runtime.h>
#include <hip/hip_bf16.h>

#define G_N 96
#define N_N 250
#define N_P 256
#define E_N 64
#define OUT_GSTRIDE (250 * 750)          // per-graph slab inside one output tensor (floats)
#define OUT_STRIDE  (96 * 250 * 750)     // 18,000,000 floats per output tensor

typedef __attribute__((ext_vector_type(4))) float floatx4;
typedef __attribute__((ext_vector_type(2))) float floatx2;
typedef __attribute__((ext_vector_type(8))) short shortx8;
typedef __attribute__((ext_vector_type(4))) short shortx4;

__device__ __forceinline__ float bf2f(unsigned short u) {
    union { unsigned int i; float f; } v; v.i = ((unsigned int)u) << 16; return v.f;
}
__device__ __forceinline__ unsigned short f2bf(float f) {
    union { float f; unsigned int i; } v; v.f = f;
    unsigned int x = v.i;
    return (unsigned short)((x + 0x7fffu + ((x >> 16) & 1u)) >> 16);  // RNE
}

// ---------------------------------------------------------------------------
// K1: nodevec = tanh(concat(hist,prior,obs) @ W + b)  -> bf16 [96][256][64]
// XCD swizzle: graph g's blocks land on XCD g/12 (same family as consumers).
// ---------------------------------------------------------------------------
__global__ __launch_bounds__(256) void k_embed(
    const float* __restrict__ hist, const float* __restrict__ prior,
    const float* __restrict__ obs, const float* __restrict__ Wemb,
    const float* __restrict__ bemb, unsigned short* __restrict__ nvb)
{
    __shared__ __attribute__((aligned(16))) float Xt[32][68];  // [k][n], pad 68
    __shared__ __attribute__((aligned(16))) float Wl[32][64];  // [k][e]
    const int t  = threadIdx.x;
    const int tx = t & 15, ty = t >> 4;
    const int b   = (blockIdx.x & 7) * 48 + (blockIdx.x >> 3);  // 384 = 8*48, bijective
    const int rr0 = b * 64;            // padded row base; 64 | 256 so g uniform
    const int g   = rr0 >> 8;
    const int n0  = rr0 & 255;

    float acc[4][4] = {};

    for (int c = 0; c < 7; ++c) {      // 7 K-chunks of 32; source boundaries align
        const float* src; int rowlen, off;
        if (c < 4)      { src = hist;  rowlen = 128; off = c << 5; }
        else if (c < 6) { src = prior; rowlen = 64;  off = (c - 4) << 5; }
        else            { src = obs;   rowlen = 32;  off = 0; }
        __syncthreads();
        {   // stage X chunk transposed: 64 rows x 32 d
            const int d  = t & 31;
            const int nb = t >> 5;
            #pragma unroll
            for (int p = 0; p < 8; ++p) {
                const int nl = nb + p * 8;
                const int n  = n0 + nl;
                float v = 0.0f;
                if (n < N_N) v = src[(size_t)(g * N_N + n) * rowlen + off + d];
                Xt[d][nl] = v;
            }
        }
        {   // stage W chunk: 32 d x 64 e
            const int e  = t & 63;
            const int db = t >> 6;
            #pragma unroll
            for (int p = 0; p < 8; ++p) {
                const int dl = db + p * 4;
                Wl[dl][e] = Wemb[(c * 32 + dl) * 64 + e];
            }
        }
        __syncthreads();
        #pragma unroll
        for (int k = 0; k < 32; ++k) {
            const float4 av = *(const float4*)&Xt[k][4 * ty];
            const float4 bv = *(const float4*)&Wl[k][4 * tx];
            const float a[4] = {av.x, av.y, av.z, av.w};
            const float b2[4] = {bv.x, bv.y, bv.z, bv.w};
            #pragma unroll
            for (int r = 0; r < 4; ++r)
                #pragma unroll
                for (int cc = 0; cc < 4; ++cc)
                    acc[r][cc] = fmaf(a[r], b2[cc], acc[r][cc]);
        }
    }
    #pragma unroll
    for (int r = 0; r < 4; ++r) {
        const int nl = 4 * ty + r;
        const int n  = n0 + nl;
        unsigned short* d2 = nvb + ((size_t)g * N_P + (n0 + nl)) * E_N + 4 * tx;
        #pragma unroll
        for (int cc = 0; cc < 4; ++cc) {
            float v = 0.0f;
            if (n < N_N) v = tanhf(acc[r][cc] + bemb[4 * tx + cc]);
            d2[cc] = f2bf(v);
        }
    }
}

// ---------------------------------------------------------------------------
// K2a: S = relu(nv @ nv^T) per graph (bf16 MFMA 16x16x32, K=64) + fp32
// rowsums. XCD swizzle matches k_pq: S lines land in the consumer XCD's L2.
// ---------------------------------------------------------------------------
__global__ __launch_bounds__(256) void k_sim(
    const unsigned short* __restrict__ nvb, unsigned short* __restrict__ Sb,
    float* __restrict__ rowsum)
{
    const int blk = (blockIdx.x & 7) * 192 + (blockIdx.x >> 3);  // 1536 = 8*192
    const int g   = blk >> 4;
    const int i0  = (blk & 15) << 4;
    const int t    = threadIdx.x;
    const int w    = t >> 6;
    const int lane = t & 63;
    const int m = lane & 15, kg = lane >> 4;

    const shortx8* nvg = (const shortx8*)(nvb + (size_t)g * N_P * E_N);
    const shortx8 a0 = nvg[(i0 + m) * 8 + kg];       // k in [8kg, 8kg+8)
    const shortx8 a1 = nvg[(i0 + m) * 8 + 4 + kg];   // k in [32+8kg, ...)

    floatx4 acc[4];
    const floatx4 zero = {0.f, 0.f, 0.f, 0.f};
    #pragma unroll
    for (int tt = 0; tt < 4; ++tt) {
        const int j = (w << 6) + (tt << 4) + m;      // B-frag: n=lane&15, row-major nv
        const shortx8 b0 = nvg[j * 8 + kg];
        const shortx8 b1 = nvg[j * 8 + 4 + kg];
        floatx4 c = zero;
        c = __builtin_amdgcn_mfma_f32_16x16x32_bf16(a0, b0, c, 0, 0, 0);
        c = __builtin_amdgcn_mfma_f32_16x16x32_bf16(a1, b1, c, 0, 0, 0);
        acc[tt] = c;
    }

    float v[4] = {0.f, 0.f, 0.f, 0.f};
    unsigned short* Sg = Sb + (size_t)g * N_P * N_P;
    #pragma unroll
    for (int tt = 0; tt < 4; ++tt) {
        #pragma unroll
        for (int r = 0; r < 4; ++r) {
            float s = acc[tt][r];
            s = s > 0.f ? s : 0.f;                   // relu
            const int il = (kg << 2) + r;            // C/D: row=(lane>>4)*4+reg
            const int j  = (w << 6) + (tt << 4) + m; // col=lane&15
            Sg[(size_t)(i0 + il) * N_P + j] = f2bf(s);
            v[r] += s;
        }
    }
    #pragma unroll
    for (int r = 0; r < 4; ++r) {                    // reduce over m (16 lanes)
        v[r] += __shfl_xor(v[r], 1);
        v[r] += __shfl_xor(v[r], 2);
        v[r] += __shfl_xor(v[r], 4);
        v[r] += __shfl_xor(v[r], 8);
    }
    __shared__ float rs[4][16];
    if (m == 0) {
        #pragma unroll
        for (int r = 0; r < 4; ++r) rs[w][(kg << 2) + r] = v[r];
    }
    __syncthreads();
    if (t < 16) rowsum[g * N_P + i0 + t] = rs[0][t] + rs[1][t] + rs[2][t] + rs[3][t];
}

// ---------------------------------------------------------------------------
// K2b: t_i = sum_j S_ij d_j ; r=1/(d_i t_i+1e-9); c=r*d; w=c*d
// Wave-per-row, fully coalesced. 96*64 blocks.
// ---------------------------------------------------------------------------
__global__ __launch_bounds__(256) void k_trans(
    const unsigned short* __restrict__ Sb, const float* __restrict__ rowsum,
    float* __restrict__ cArr, float* __restrict__ wArr)
{
    const int blk = (blockIdx.x & 7) * 768 + (blockIdx.x >> 3);  // XCD swizzle, 6144 blocks
    const int g  = blk >> 6;
    const int r0 = (blk & 63) << 2;      // 4 rows per block, one per wave
    const int t = threadIdx.x;
    const int w = t >> 6, lane = t & 63;
    __shared__ __attribute__((aligned(16))) float dL[N_P];
    dL[t] = rsqrtf(rowsum[g * N_P + t] + 1e-9f);
    __syncthreads();
    const int row = r0 + w;
    const shortx4 sv = *(const shortx4*)(Sb + (size_t)g * N_P * N_P
                                         + (size_t)row * N_P + lane * 4);
    const float4 dv = *(const float4*)&dL[lane * 4];
    float a = bf2f((unsigned short)sv[0]) * dv.x
            + bf2f((unsigned short)sv[1]) * dv.y
            + bf2f((unsigned short)sv[2]) * dv.z
            + bf2f((unsigned short)sv[3]) * dv.w;
    #pragma unroll
    for (int s = 32; s; s >>= 1) a += __shfl_xor(a, s);
    if (lane == 0) {
        const float d = dL[row];
        const float r = 1.0f / (d * a + 1e-9f);
        const float c = r * d;
        cArr[g * N_P + row] = c;
        wArr[g * N_P + row] = c * d;
    }
}

// ---------------------------------------------------------------------------
// K3 v9: column-tile-ordered accumulation so q ALSO overlaps compute.
//   for tt in 0..3: { for kb in 0..7: mfma(aw[kb], B(tt,kb)) ; write q(tt) }
// q for tile tt streams while tile tt+1 computes; p is interleaved into
// tt=0's kb loop (r11/r12-verified). All 288 MB of stores now overlap MFMA.
// B fragments load directly from L2-hot S (r8-verified pattern, same total
// L2 traffic as staging); A fragments pre-folded once into 8 regs.
// qT is double-buffered [2][16][68] -> ONE barrier per tt (write tt and
// read tt-1 use different buffers; barrier(tt) orders read(tt-1) before
// any wave's write(tt+1)). LDS 10.9 KB, ~5 blocks/CU.
// ---------------------------------------------------------------------------
__global__ __launch_bounds__(256) void k_pq(
    const unsigned short* __restrict__ Sb, const float* __restrict__ rowsum,
    const float* __restrict__ cArr, const float* __restrict__ wArr,
    float* __restrict__ out)
{
    const int blk = (blockIdx.x & 7) * 192 + (blockIdx.x >> 3);  // XCD swizzle, 1536 blocks
    const int g   = blk >> 4;
    const int i0  = (blk & 15) << 4;     // 16-row stripe
    const int t    = threadIdx.x;
    const int w    = t >> 6;
    const int lane = t & 63;
    const int m = lane & 15, kg = lane >> 4;

    __shared__ __attribute__((aligned(16))) float wL[N_P];
    __shared__ __attribute__((aligned(16))) float cC[N_P];
    __shared__ float dR16[16];
    __shared__ __attribute__((aligned(16))) float qT[2][16][68];  // dbuf col-block transpose

    wL[t] = wArr[g * N_P + t];
    cC[t] = cArr[g * N_P + t];
    if (t < 16) dR16[t] = rsqrtf(rowsum[g * N_P + i0 + t] + 1e-9f);
    __syncthreads();

    const unsigned short* Sg = Sb + (size_t)g * N_P * N_P;
    float* o0 = out + (size_t)g * OUT_GSTRIDE;
    float* o1 = o0 + (size_t)OUT_STRIDE;
    float* o2 = o0 + 2 * (size_t)OUT_STRIDE;
    float* o3 = o0 + 3 * (size_t)OUT_STRIDE;
    const int c0 = lane << 2;

    // ---- preload + w-fold the 8 A fragments (row i0+m, k-slice kg*8 per kb)
    shortx8 aw[8];
    const unsigned short* aRow = Sg + (size_t)(i0 + m) * N_P + (kg << 3);
    #pragma unroll
    for (int kb = 0; kb < 8; ++kb) {
        const shortx8 a = *(const shortx8*)(aRow + kb * 32);
        const float4 w0 = *(const float4*)&wL[kb * 32 + (kg << 3)];
        const float4 w1 = *(const float4*)&wL[kb * 32 + (kg << 3) + 4];
        const float wv[8] = {w0.x, w0.y, w0.z, w0.w, w1.x, w1.y, w1.z, w1.w};
        #pragma unroll
        for (int u = 0; u < 8; ++u)
            aw[kb][u] = (short)f2bf(bf2f((unsigned short)a[u]) * wv[u]);
    }

    for (int tt = 0; tt < 4; ++tt) {
        // ---- accumulate column tile tt over all K
        floatx4 acc = {0.f, 0.f, 0.f, 0.f};
        const int j = (w << 6) + (tt << 4) + m;
        const unsigned short* bRow = Sg + (size_t)j * N_P + (kg << 3);
        #pragma unroll
        for (int kb = 0; kb < 8; ++kb) {
            const shortx8 b = *(const shortx8*)(bRow + kb * 32);
            acc = __builtin_amdgcn_mfma_f32_16x16x32_bf16(aw[kb], b, acc, 0, 0, 0);
            if (tt == 0) {
                // interleaved p-write (r11 scheme): wave w -> row 2kb+(w>>1),
                // tensor w&1. Uses only Sg/cC/dR16 -> independent of MFMA.
                const int row = (kb << 1) + (w >> 1);
                const int i   = i0 + row;
                if (i < N_N && c0 < 252) {
                    const float dI = dR16[row];
                    const shortx4 sv = *(const shortx4*)(Sg + (size_t)i * N_P + c0);
                    const float4 cc4 = *(const float4*)&cC[c0];
                    const float p0 = (i == c0)     ? 0.f : dI * bf2f((unsigned short)sv[0]) * cc4.x;
                    const float p1 = (i == c0 + 1) ? 0.f : dI * bf2f((unsigned short)sv[1]) * cc4.y;
                    const float p2 = (i == c0 + 2) ? 0.f : dI * bf2f((unsigned short)sv[2]) * cc4.z;
                    const float p3 = (i == c0 + 3) ? 0.f : dI * bf2f((unsigned short)sv[3]) * cc4.w;
                    const floatx2 pxy = {p0, p1}, pzw = {p2, p3};
                    float* b0 = ((w & 1) ? o2 : o0) + (size_t)i * 750 + c0;
                    #pragma unroll
                    for (int rep = 0; rep < 3; ++rep) {
                        const int o = rep * 250;
                        *(floatx2*)(b0 + o) = pxy;
                        if (lane < 62) *(floatx2*)(b0 + o + 2) = pzw;
                    }
                }
            }
        }

        // ---- transpose q tile via dbuf LDS (write buf tt&1)
        const int bsel = tt & 1;
        #pragma unroll
        for (int r = 0; r < 4; ++r) {
            const int lrow = (kg << 2) + r;           // C/D row = (lane>>4)*4+reg
            float qv = acc[r] * dR16[lrow] * cC[j];   // col = j
            if (i0 + lrow == j) qv = 0.f;
            qT[bsel][lrow][(w << 4) + m] = qv;
        }
        __syncthreads();

        // ---- stream q tile tt (overlaps tile tt+1's compute)
        // lanes 0-31 / 32-63 take different rows; lane covers 2 cols.
        const int half = lane >> 5;
        const int cl   = (lane & 31) << 1;            // col_local, even
        const int jj   = ((cl >> 4) << 6) + (tt << 4) + (cl & 15);  // global col
        if (jj + 1 < N_N) {
            #pragma unroll
            for (int pr = 0; pr < 2; ++pr) {
                const int row = w + (half << 2) + (pr << 3);  // {w,w+4,w+8,w+12}
                const int i   = i0 + row;
                if (i >= N_N) continue;
                const floatx2 qv = *(const floatx2*)&qT[bsel][row][cl];
                float* b1 = o1 + (size_t)i * 750 + jj;
                float* b3 = o3 + (size_t)i * 750 + jj;
                #pragma unroll
                for (int rep = 0; rep < 3; ++rep) {
                    const int o = rep * 250;
                    *(floatx2*)(b1 + o) = qv;
                    *(floatx2*)(b3 + o) = qv;
                }
            }
        }
    }
}

extern "C" void kernel_launch(void* const* d_in, const int* in_sizes, int n_in,
                              void* d_out, int out_size, void* d_ws, size_t ws_size,
                              hipStream_t stream) {
    const float* hist  = (const float*)d_in[0];
    const float* prior = (const float*)d_in[1];
    const float* obs   = (const float*)d_in[2];
    const float* Wemb  = (const float*)d_in[3];
    const float* bemb  = (const float*)d_in[4];
    float* out = (float*)d_out;

    char* p = (char*)d_ws;
    unsigned short* nvb = (unsigned short*)p; p += (size_t)G_N * N_P * E_N * 2;   // 3.1 MB
    unsigned short* Sb  = (unsigned short*)p; p += (size_t)G_N * N_P * N_P * 2;   // 12.6 MB
    float* rowsum = (float*)p; p += (size_t)G_N * N_P * 4;
    float* cArr   = (float*)p; p += (size_t)G_N * N_P * 4;
    float* wArr   = (float*)p; p += (size_t)G_N * N_P * 4;
    // total ~16 MB of ws

    k_embed<<<dim3(G_N * N_P / 64), dim3(256), 0, stream>>>(hist, prior, obs, Wemb, bemb, nvb);
    k_sim  <<<dim3(G_N * 16),       dim3(256), 0, stream>>>(nvb, Sb, rowsum);
    k_trans<<<dim3(G_N * 64),       dim3(256), 0, stream>>>(Sb, rowsum, cArr, wArr);
    k_pq   <<<dim3(G_N * 16),       dim3(256), 0, stream>>>(Sb, rowsum, cArr, wArr, out);
}

// Round 14
// 363.685 us; speedup vs baseline: 1.2432x; 1.2432x over previous
//
#include <hip/hip_runtime.h>
#include <hip/hip_bf16.h>

#define G_N 96
#define N_N 250
#define N_P 256
#define E_N 64
#define OUT_GSTRIDE (250 * 750)          // per-graph slab inside one output tensor (floats)
#define OUT_STRIDE  (96 * 250 * 750)     // 18,000,000 floats per output tensor

typedef __attribute__((ext_vector_type(4))) float floatx4;
typedef __attribute__((ext_vector_type(2))) float floatx2;
typedef __attribute__((ext_vector_type(8))) short shortx8;
typedef __attribute__((ext_vector_type(4))) short shortx4;

__device__ __forceinline__ float bf2f(unsigned short u) {
    union { unsigned int i; float f; } v; v.i = ((unsigned int)u) << 16; return v.f;
}
__device__ __forceinline__ unsigned short f2bf(float f) {
    union { float f; unsigned int i; } v; v.f = f;
    unsigned int x = v.i;
    return (unsigned short)((x + 0x7fffu + ((x >> 16) & 1u)) >> 16);  // RNE
}

// ---------------------------------------------------------------------------
// K1: nodevec = tanh(concat(hist,prior,obs) @ W + b)  -> bf16 [96][256][64]
// XCD swizzle: graph g's blocks land on XCD g/12 (same family as consumers).
// ---------------------------------------------------------------------------
__global__ __launch_bounds__(256) void k_embed(
    const float* __restrict__ hist, const float* __restrict__ prior,
    const float* __restrict__ obs, const float* __restrict__ Wemb,
    const float* __restrict__ bemb, unsigned short* __restrict__ nvb)
{
    __shared__ __attribute__((aligned(16))) float Xt[32][68];  // [k][n], pad 68
    __shared__ __attribute__((aligned(16))) float Wl[32][64];  // [k][e]
    const int t  = threadIdx.x;
    const int tx = t & 15, ty = t >> 4;
    const int b   = (blockIdx.x & 7) * 48 + (blockIdx.x >> 3);  // 384 = 8*48, bijective
    const int rr0 = b * 64;            // padded row base; 64 | 256 so g uniform
    const int g   = rr0 >> 8;
    const int n0  = rr0 & 255;

    float acc[4][4] = {};

    for (int c = 0; c < 7; ++c) {      // 7 K-chunks of 32; source boundaries align
        const float* src; int rowlen, off;
        if (c < 4)      { src = hist;  rowlen = 128; off = c << 5; }
        else if (c < 6) { src = prior; rowlen = 64;  off = (c - 4) << 5; }
        else            { src = obs;   rowlen = 32;  off = 0; }
        __syncthreads();
        {   // stage X chunk transposed: 64 rows x 32 d
            const int d  = t & 31;
            const int nb = t >> 5;
            #pragma unroll
            for (int p = 0; p < 8; ++p) {
                const int nl = nb + p * 8;
                const int n  = n0 + nl;
                float v = 0.0f;
                if (n < N_N) v = src[(size_t)(g * N_N + n) * rowlen + off + d];
                Xt[d][nl] = v;
            }
        }
        {   // stage W chunk: 32 d x 64 e
            const int e  = t & 63;
            const int db = t >> 6;
            #pragma unroll
            for (int p = 0; p < 8; ++p) {
                const int dl = db + p * 4;
                Wl[dl][e] = Wemb[(c * 32 + dl) * 64 + e];
            }
        }
        __syncthreads();
        #pragma unroll
        for (int k = 0; k < 32; ++k) {
            const float4 av = *(const float4*)&Xt[k][4 * ty];
            const float4 bv = *(const float4*)&Wl[k][4 * tx];
            const float a[4] = {av.x, av.y, av.z, av.w};
            const float b2[4] = {bv.x, bv.y, bv.z, bv.w};
            #pragma unroll
            for (int r = 0; r < 4; ++r)
                #pragma unroll
                for (int cc = 0; cc < 4; ++cc)
                    acc[r][cc] = fmaf(a[r], b2[cc], acc[r][cc]);
        }
    }
    #pragma unroll
    for (int r = 0; r < 4; ++r) {
        const int nl = 4 * ty + r;
        const int n  = n0 + nl;
        unsigned short* d2 = nvb + ((size_t)g * N_P + (n0 + nl)) * E_N + 4 * tx;
        #pragma unroll
        for (int cc = 0; cc < 4; ++cc) {
            float v = 0.0f;
            if (n < N_N) v = tanhf(acc[r][cc] + bemb[4 * tx + cc]);
            d2[cc] = f2bf(v);
        }
    }
}

// ---------------------------------------------------------------------------
// K2a: S = relu(nv @ nv^T) per graph (bf16 MFMA 16x16x32, K=64) + fp32
// rowsums. XCD swizzle matches k_pq: S lines land in the consumer XCD's L2.
// ---------------------------------------------------------------------------
__global__ __launch_bounds__(256) void k_sim(
    const unsigned short* __restrict__ nvb, unsigned short* __restrict__ Sb,
    float* __restrict__ rowsum)
{
    const int blk = (blockIdx.x & 7) * 192 + (blockIdx.x >> 3);  // 1536 = 8*192
    const int g   = blk >> 4;
    const int i0  = (blk & 15) << 4;
    const int t    = threadIdx.x;
    const int w    = t >> 6;
    const int lane = t & 63;
    const int m = lane & 15, kg = lane >> 4;

    const shortx8* nvg = (const shortx8*)(nvb + (size_t)g * N_P * E_N);
    const shortx8 a0 = nvg[(i0 + m) * 8 + kg];       // k in [8kg, 8kg+8)
    const shortx8 a1 = nvg[(i0 + m) * 8 + 4 + kg];   // k in [32+8kg, ...)

    floatx4 acc[4];
    const floatx4 zero = {0.f, 0.f, 0.f, 0.f};
    #pragma unroll
    for (int tt = 0; tt < 4; ++tt) {
        const int j = (w << 6) + (tt << 4) + m;      // B-frag: n=lane&15, row-major nv
        const shortx8 b0 = nvg[j * 8 + kg];
        const shortx8 b1 = nvg[j * 8 + 4 + kg];
        floatx4 c = zero;
        c = __builtin_amdgcn_mfma_f32_16x16x32_bf16(a0, b0, c, 0, 0, 0);
        c = __builtin_amdgcn_mfma_f32_16x16x32_bf16(a1, b1, c, 0, 0, 0);
        acc[tt] = c;
    }

    float v[4] = {0.f, 0.f, 0.f, 0.f};
    unsigned short* Sg = Sb + (size_t)g * N_P * N_P;
    #pragma unroll
    for (int tt = 0; tt < 4; ++tt) {
        #pragma unroll
        for (int r = 0; r < 4; ++r) {
            float s = acc[tt][r];
            s = s > 0.f ? s : 0.f;                   // relu
            const int il = (kg << 2) + r;            // C/D: row=(lane>>4)*4+reg
            const int j  = (w << 6) + (tt << 4) + m; // col=lane&15
            Sg[(size_t)(i0 + il) * N_P + j] = f2bf(s);
            v[r] += s;
        }
    }
    #pragma unroll
    for (int r = 0; r < 4; ++r) {                    // reduce over m (16 lanes)
        v[r] += __shfl_xor(v[r], 1);
        v[r] += __shfl_xor(v[r], 2);
        v[r] += __shfl_xor(v[r], 4);
        v[r] += __shfl_xor(v[r], 8);
    }
    __shared__ float rs[4][16];
    if (m == 0) {
        #pragma unroll
        for (int r = 0; r < 4; ++r) rs[w][(kg << 2) + r] = v[r];
    }
    __syncthreads();
    if (t < 16) rowsum[g * N_P + i0 + t] = rs[0][t] + rs[1][t] + rs[2][t] + rs[3][t];
}

// ---------------------------------------------------------------------------
// K2b: t_i = sum_j S_ij d_j ; r=1/(d_i t_i+1e-9); c=r*d; w=c*d
// Wave-per-row, fully coalesced. 96*64 blocks.
// ---------------------------------------------------------------------------
__global__ __launch_bounds__(256) void k_trans(
    const unsigned short* __restrict__ Sb, const float* __restrict__ rowsum,
    float* __restrict__ cArr, float* __restrict__ wArr)
{
    const int blk = (blockIdx.x & 7) * 768 + (blockIdx.x >> 3);  // XCD swizzle, 6144 blocks
    const int g  = blk >> 6;
    const int r0 = (blk & 63) << 2;      // 4 rows per block, one per wave
    const int t = threadIdx.x;
    const int w = t >> 6, lane = t & 63;
    __shared__ __attribute__((aligned(16))) float dL[N_P];
    dL[t] = rsqrtf(rowsum[g * N_P + t] + 1e-9f);
    __syncthreads();
    const int row = r0 + w;
    const shortx4 sv = *(const shortx4*)(Sb + (size_t)g * N_P * N_P
                                         + (size_t)row * N_P + lane * 4);
    const float4 dv = *(const float4*)&dL[lane * 4];
    float a = bf2f((unsigned short)sv[0]) * dv.x
            + bf2f((unsigned short)sv[1]) * dv.y
            + bf2f((unsigned short)sv[2]) * dv.z
            + bf2f((unsigned short)sv[3]) * dv.w;
    #pragma unroll
    for (int s = 32; s; s >>= 1) a += __shfl_xor(a, s);
    if (lane == 0) {
        const float d = dL[row];
        const float r = 1.0f / (d * a + 1e-9f);
        const float c = r * d;
        cArr[g * N_P + row] = c;
        wArr[g * N_P + row] = c * d;
    }
}

// ---------------------------------------------------------------------------
// K3 v7 (REVERT to r11 best, 363.1 us): fused structure + phase overlap.
//  - LDS 39.6 KB (pAll dropped; p recomputed from global S-row read)
//    -> 4 blocks/CU.
//  - Phase stagger by (blk&1): odd blocks [write-p -> compute -> write-q],
//    even blocks [compute -> write-q -> write-p]. At any instant ~half the
//    resident blocks stream stores while the other half compute.
//  - write paths: q via qAll (conflict-free b128 reads, float2 stores),
//    p via coalesced shortx4 S + float2 stores.
// r12 (p interleaved into kb loop) was null; r13 (per-column-tile q
// overlap, no Bs staging) regressed 2x -- this version is the measured
// optimum of the 9-variant k_pq family.
// ---------------------------------------------------------------------------
__global__ __launch_bounds__(256) void k_pq(
    const unsigned short* __restrict__ Sb, const float* __restrict__ rowsum,
    const float* __restrict__ cArr, const float* __restrict__ wArr,
    float* __restrict__ out)
{
    const int blk = (blockIdx.x & 7) * 192 + (blockIdx.x >> 3);  // XCD swizzle, 1536 blocks
    const int g   = blk >> 4;
    const int i0  = (blk & 15) << 4;     // 16-row stripe
    const int t    = threadIdx.x;
    const int w    = t >> 6;
    const int lane = t & 63;
    const int m = lane & 15, kg = lane >> 4;

    __shared__ __attribute__((aligned(16))) unsigned short As[16][40];   // stripe rows x 32k
    __shared__ __attribute__((aligned(16))) unsigned short Bs[256][40];  // all rows x 32k
    __shared__ __attribute__((aligned(16))) float wL[N_P];
    __shared__ __attribute__((aligned(16))) float cC[N_P];
    __shared__ float dR16[16];
    __shared__ __attribute__((aligned(16))) float qAll[16][260];  // 1040B row stride

    wL[t] = wArr[g * N_P + t];
    cC[t] = cArr[g * N_P + t];
    if (t < 16) dR16[t] = rsqrtf(rowsum[g * N_P + i0 + t] + 1e-9f);
    __syncthreads();

    const unsigned short* Sg = Sb + (size_t)g * N_P * N_P;
    float* o0 = out + (size_t)g * OUT_GSTRIDE;
    float* o1 = o0 + (size_t)OUT_STRIDE;
    float* o2 = o0 + 2 * (size_t)OUT_STRIDE;
    float* o3 = o0 + 3 * (size_t)OUT_STRIDE;
    const int c0 = lane << 2;

    auto writeP = [&]() {
        if (c0 >= 252) return;                     // lane 63 idle; no barriers inside
        #pragma unroll
        for (int rr = 0; rr < 4; ++rr) {
            const int row = (rr << 2) + w;
            const int i   = i0 + row;
            if (i >= N_N) continue;                // wave-uniform
            const float dI = dR16[row];
            const shortx4 sv = *(const shortx4*)(Sg + (size_t)i * N_P + c0);
            const float4 cc4 = *(const float4*)&cC[c0];
            const float p0 = (i == c0)     ? 0.f : dI * bf2f((unsigned short)sv[0]) * cc4.x;
            const float p1 = (i == c0 + 1) ? 0.f : dI * bf2f((unsigned short)sv[1]) * cc4.y;
            const float p2 = (i == c0 + 2) ? 0.f : dI * bf2f((unsigned short)sv[2]) * cc4.z;
            const float p3 = (i == c0 + 3) ? 0.f : dI * bf2f((unsigned short)sv[3]) * cc4.w;
            const floatx2 pxy = {p0, p1}, pzw = {p2, p3};
            float* b0 = o0 + (size_t)i * 750 + c0;
            float* b2 = o2 + (size_t)i * 750 + c0;
            #pragma unroll
            for (int rep = 0; rep < 3; ++rep) {
                const int o = rep * 250;
                *(floatx2*)(b0 + o) = pxy;
                *(floatx2*)(b2 + o) = pxy;
                if (lane < 62) {                   // zw cols valid (<=247)
                    *(floatx2*)(b0 + o + 2) = pzw;
                    *(floatx2*)(b2 + o + 2) = pzw;
                }
            }
        }
    };

    const bool pfirst = (blk & 1) != 0;
    if (pfirst) writeP();

    floatx4 acc[4];
    const floatx4 zero = {0.f, 0.f, 0.f, 0.f};
    #pragma unroll
    for (int tt = 0; tt < 4; ++tt) acc[tt] = zero;

    for (int kb = 0; kb < 8; ++kb) {
        __syncthreads();
        if (t < 64) {      // stage A chunk: 16 rows x 32 k (64 x uint4)
            const int row = t >> 2, c4 = t & 3;
            *(uint4*)&As[row][c4 * 8] =
                *(const uint4*)(Sg + (size_t)(i0 + row) * N_P + kb * 32 + c4 * 8);
        }
        #pragma unroll
        for (int q4 = 0; q4 < 4; ++q4) {   // stage B chunk: 256 rows x 32 k (1024 x uint4)
            const int u = t + (q4 << 8);
            const int row = u >> 2, c4 = u & 3;
            *(uint4*)&Bs[row][c4 * 8] =
                *(const uint4*)(Sg + (size_t)row * N_P + kb * 32 + c4 * 8);
        }
        __syncthreads();
        // MFMA: A-frag (w folded), B-frags per wave column block
        const shortx8 a = *(const shortx8*)&As[m][kg << 3];
        const float4 w0 = *(const float4*)&wL[kb * 32 + (kg << 3)];
        const float4 w1 = *(const float4*)&wL[kb * 32 + (kg << 3) + 4];
        const float wv[8] = {w0.x, w0.y, w0.z, w0.w, w1.x, w1.y, w1.z, w1.w};
        shortx8 aw;
        #pragma unroll
        for (int u = 0; u < 8; ++u)
            aw[u] = (short)f2bf(bf2f((unsigned short)a[u]) * wv[u]);
        #pragma unroll
        for (int tt = 0; tt < 4; ++tt) {
            const shortx8 b = *(const shortx8*)&Bs[(w << 6) + (tt << 4) + m][kg << 3];
            acc[tt] = __builtin_amdgcn_mfma_f32_16x16x32_bf16(aw, b, acc[tt], 0, 0, 0);
        }
    }

    // q -> LDS (C/D layout: row = kg*4+r in stripe, col = w*64 + tt*16 + m)
    #pragma unroll
    for (int tt = 0; tt < 4; ++tt) {
        #pragma unroll
        for (int r = 0; r < 4; ++r) {
            const int lrow = (kg << 2) + r;
            const int col  = (w << 6) + (tt << 4) + m;
            float qv = acc[tt][r] * dR16[lrow] * cC[col];
            if (i0 + lrow == col) qv = 0.f;
            qAll[lrow][col] = qv;
        }
    }
    __syncthreads();

    // write q: wave w owns rows {w, w+4, w+8, w+12}; lane L cols 4L..4L+3
    #pragma unroll
    for (int rr = 0; rr < 4; ++rr) {
        const int row = (rr << 2) + w;
        const int i   = i0 + row;
        if (i >= N_N) continue;                    // wave-uniform
        const floatx4 q4 = *(const floatx4*)&qAll[row][c0];  // c0<=252, +3 < 260
        if (c0 >= 252) continue;                   // lane 63 idle
        const floatx2 qxy = {q4[0], q4[1]}, qzw = {q4[2], q4[3]};
        float* b1 = o1 + (size_t)i * 750 + c0;
        float* b3 = o3 + (size_t)i * 750 + c0;
        #pragma unroll
        for (int rep = 0; rep < 3; ++rep) {
            const int o = rep * 250;
            *(floatx2*)(b1 + o) = qxy;
            *(floatx2*)(b3 + o) = qxy;
            if (lane < 62) {
                *(floatx2*)(b1 + o + 2) = qzw;
                *(floatx2*)(b3 + o + 2) = qzw;
            }
        }
    }

    if (!pfirst) writeP();
}

extern "C" void kernel_launch(void* const* d_in, const int* in_sizes, int n_in,
                              void* d_out, int out_size, void* d_ws, size_t ws_size,
                              hipStream_t stream) {
    const float* hist  = (const float*)d_in[0];
    const float* prior = (const float*)d_in[1];
    const float* obs   = (const float*)d_in[2];
    const float* Wemb  = (const float*)d_in[3];
    const float* bemb  = (const float*)d_in[4];
    float* out = (float*)d_out;

    char* p = (char*)d_ws;
    unsigned short* nvb = (unsigned short*)p; p += (size_t)G_N * N_P * E_N * 2;   // 3.1 MB
    unsigned short* Sb  = (unsigned short*)p; p += (size_t)G_N * N_P * N_P * 2;   // 12.6 MB
    float* rowsum = (float*)p; p += (size_t)G_N * N_P * 4;
    float* cArr   = (float*)p; p += (size_t)G_N * N_P * 4;
    float* wArr   = (float*)p; p += (size_t)G_N * N_P * 4;
    // total ~16 MB of ws

    k_embed<<<dim3(G_N * N_P / 64), dim3(256), 0, stream>>>(hist, prior, obs, Wemb, bemb, nvb);
    k_sim  <<<dim3(G_N * 16),       dim3(256), 0, stream>>>(nvb, Sb, rowsum);
    k_trans<<<dim3(G_N * 64),       dim3(256), 0, stream>>>(Sb, rowsum, cArr, wArr);
    k_pq   <<<dim3(G_N * 16),       dim3(256), 0, stream>>>(Sb, rowsum, cArr, wArr, out);
}